// Round 1
// baseline (42.681 us; speedup 1.0000x reference)
//
#include <hip/hip_runtime.h>
#include <math.h>

// out = [h0, h1, atan2(softsign(h2), softsign(h3))]
// h = W @ [x0, x1, x2, sin(x2), cos(x2), 1] + b
// Memory-bound: 12 B in + 12 B out per row. 4 rows/thread -> 3x float4 each way.

__global__ __launch_bounds__(256) void net_main_kernel(
    const float4* __restrict__ x4,
    const float*  __restrict__ W,
    const float*  __restrict__ bias,
    float4*       __restrict__ o4,
    int nquad)
{
    const int t = blockIdx.x * blockDim.x + threadIdx.x;
    if (t >= nquad) return;

    // Uniform loads -> scalar (s_load) path; fold ones-column + bias.
    float w[4][5];
    float wb[4];
#pragma unroll
    for (int r = 0; r < 4; ++r) {
#pragma unroll
        for (int c = 0; c < 5; ++c) w[r][c] = W[r * 6 + c];
        wb[r] = W[r * 6 + 5] + bias[r];
    }

    const float4 qa = x4[3 * t + 0];
    const float4 qb = x4[3 * t + 1];
    const float4 qc = x4[3 * t + 2];

    const float rx[4][3] = {
        {qa.x, qa.y, qa.z},
        {qa.w, qb.x, qb.y},
        {qb.z, qb.w, qc.x},
        {qc.y, qc.z, qc.w},
    };

    float res[4][3];
#pragma unroll
    for (int i = 0; i < 4; ++i) {
        const float x0 = rx[i][0];
        const float x1 = rx[i][1];
        const float an = rx[i][2];
        const float s = __sinf(an);
        const float c = __cosf(an);

        float h[4];
#pragma unroll
        for (int r = 0; r < 4; ++r) {
            float acc = wb[r];
            acc = fmaf(c,  w[r][4], acc);
            acc = fmaf(s,  w[r][3], acc);
            acc = fmaf(an, w[r][2], acc);
            acc = fmaf(x1, w[r][1], acc);
            acc = fmaf(x0, w[r][0], acc);
            h[r] = acc;
        }

        const float ss2 = h[2] / (1.0f + fabsf(h[2]));
        const float ss3 = h[3] / (1.0f + fabsf(h[3]));

        res[i][0] = h[0];
        res[i][1] = h[1];
        res[i][2] = atan2f(ss2, ss3);
    }

    o4[3 * t + 0] = make_float4(res[0][0], res[0][1], res[0][2], res[1][0]);
    o4[3 * t + 1] = make_float4(res[1][1], res[1][2], res[2][0], res[2][1]);
    o4[3 * t + 2] = make_float4(res[2][2], res[3][0], res[3][1], res[3][2]);
}

// Tail kernel for rows not covered by the 4-row vector path (B % 4 != 0).
__global__ void net_tail_kernel(
    const float* __restrict__ x,
    const float* __restrict__ W,
    const float* __restrict__ bias,
    float*       __restrict__ out,
    int row0, int nrows)
{
    const int i = blockIdx.x * blockDim.x + threadIdx.x;
    if (i >= nrows) return;
    const int row = row0 + i;

    const float x0 = x[row * 3 + 0];
    const float x1 = x[row * 3 + 1];
    const float an = x[row * 3 + 2];
    const float s = __sinf(an);
    const float c = __cosf(an);

    float h[4];
#pragma unroll
    for (int r = 0; r < 4; ++r) {
        float acc = W[r * 6 + 5] + bias[r];
        acc = fmaf(c,  W[r * 6 + 4], acc);
        acc = fmaf(s,  W[r * 6 + 3], acc);
        acc = fmaf(an, W[r * 6 + 2], acc);
        acc = fmaf(x1, W[r * 6 + 1], acc);
        acc = fmaf(x0, W[r * 6 + 0], acc);
        h[r] = acc;
    }
    const float ss2 = h[2] / (1.0f + fabsf(h[2]));
    const float ss3 = h[3] / (1.0f + fabsf(h[3]));
    out[row * 3 + 0] = h[0];
    out[row * 3 + 1] = h[1];
    out[row * 3 + 2] = atan2f(ss2, ss3);
}

extern "C" void kernel_launch(void* const* d_in, const int* in_sizes, int n_in,
                              void* d_out, int out_size, void* d_ws, size_t ws_size,
                              hipStream_t stream) {
    const float* x    = (const float*)d_in[0];
    const float* W    = (const float*)d_in[1];
    const float* bias = (const float*)d_in[2];
    float* out        = (float*)d_out;

    const int B = in_sizes[0] / 3;          // number of rows
    const int nquad = B / 4;                // 4-row groups
    const int tail_rows = B - nquad * 4;

    if (nquad > 0) {
        const int block = 256;
        const int grid = (nquad + block - 1) / block;
        net_main_kernel<<<grid, block, 0, stream>>>(
            (const float4*)x, W, bias, (float4*)out, nquad);
    }
    if (tail_rows > 0) {
        net_tail_kernel<<<1, 64, 0, stream>>>(x, W, bias, out, nquad * 4, tail_rows);
    }
}